// Round 12
// baseline (251.443 us; speedup 1.0000x reference)
//
#include <hip/hip_runtime.h>

#define TOKENS 16384
#define THALF 8192
#define INF 2048
#define OUTF 2048
#define RANK 32
#define BM 256
#define BN 256
#define NPER 32     // 2048 / 64 f16 per K-tile

typedef int   int32x4  __attribute__((ext_vector_type(4)));
typedef int   int32x2  __attribute__((ext_vector_type(2)));
typedef float floatx4  __attribute__((ext_vector_type(4)));
typedef short bf16x8   __attribute__((ext_vector_type(8)));
typedef _Float16 f16x8 __attribute__((ext_vector_type(8)));

typedef __attribute__((address_space(1))) const void gconst_t;
typedef __attribute__((address_space(3))) void ldsv_t;

__device__ __forceinline__ void gload_lds16(const void* g, void* l) {
  __builtin_amdgcn_global_load_lds((gconst_t*)g, (ldsv_t*)l, 16, 0, 0);
}

__device__ __forceinline__ unsigned short f2bf(float f) {
  unsigned u = __float_as_uint(f);
  unsigned r = (u + 0x7FFFu + ((u >> 16) & 1u)) >> 16;
  return (unsigned short)r;
}

// ---------------- kernel 1: unpack int4 + fold wscales -> wdq f16 ----------------
__global__ __launch_bounds__(256) void unpack_kernel(const int* __restrict__ qw,
                                                     const float* __restrict__ wsc,
                                                     _Float16* __restrict__ wdq) {
  int idx = blockIdx.x * 256 + threadIdx.x;   // 131072 threads, 32 channels each
  int o = idx >> 6;
  int ch = idx & 63;                          // 32-channel chunk -> group = ch>>1
  float ws = wsc[(size_t)(ch >> 1) * OUTF + o];
  const int4* src = (const int4*)qw + (size_t)idx * 4;
  _Float16* dst = wdq + (size_t)o * INF + ch * 32;
#pragma unroll
  for (int q = 0; q < 4; ++q) {
    int4 v = src[q];
    int e[4] = {v.x, v.y, v.z, v.w};
    alignas(16) _Float16 h[8];
#pragma unroll
    for (int j = 0; j < 4; ++j) {
      int lo = ((int)((unsigned)e[j] << 28)) >> 28;
      int hi = ((int)((unsigned)e[j] << 24)) >> 28;
      h[2 * j]     = (_Float16)((float)lo * ws);
      h[2 * j + 1] = (_Float16)((float)hi * ws);
    }
    *(int4*)(dst + q * 8) = *(const int4*)h;
  }
}

// ---------------- kernel 1b: pd [2048][32] f32 -> pdT [32][2048] bf16 ----------------
__global__ __launch_bounds__(256) void prep_pdT(const float* __restrict__ pd,
                                                unsigned short* __restrict__ pdT) {
  int idx = blockIdx.x * 256 + threadIdx.x;   // 65536 elements
  int r = idx >> 11, c = idx & 2047;
  pdT[idx] = f2bf(pd[(size_t)c * RANK + r]);
}

// ---------------- kernel 2: coalesced quant -> xdq f16 + MFMA down-projection ----------------
__global__ __launch_bounds__(256) void quant_kernel(
    const float* __restrict__ x, const float* __restrict__ smooth,
    const unsigned short* __restrict__ pdT,
    _Float16* __restrict__ xdq, float* __restrict__ tdown, int tbase) {
  __shared__ char lds[32768];   // xs [32][256] bf16 swz @0, pdT chunk [32][256] bf16 swz @16384
  int tid = threadIdx.x, lane = tid & 63, wid = tid >> 6;
  int t0rel = blockIdx.x * 32;
  int mi = wid >> 1, ni = wid & 1;
  floatx4 acc = {0.f, 0.f, 0.f, 0.f};

  floatx4 xv[8];
  floatx4 sm;
  int32x4 pv[4];

  auto issue_loads = [&](int kc) {
    const float* xb = x + (size_t)(tbase + t0rel + wid * 8) * INF + kc * 256 + lane * 4;
#pragma unroll
    for (int r = 0; r < 8; ++r) xv[r] = *(const floatx4*)(xb + r * INF);
    sm = *(const floatx4*)(smooth + kc * 256 + lane * 4);
#pragma unroll
    for (int q = 0; q < 4; ++q) {
      int flat = tid + q * 256;
      int row = flat >> 5, c16 = flat & 31;
      pv[q] = *(const int32x4*)((const char*)pdT + (size_t)row * 4096 + kc * 512 + c16 * 16);
    }
  };

  issue_loads(0);

  for (int kc = 0; kc < 8; ++kc) {
    floatx4 rsm;
    rsm[0] = 1.0f / sm[0]; rsm[1] = 1.0f / sm[1];
    rsm[2] = 1.0f / sm[2]; rsm[3] = 1.0f / sm[3];
#pragma unroll
    for (int q = 0; q < 4; ++q) {
      int flat = tid + q * 256;
      int row = flat >> 5, c16 = flat & 31;
      int byte = (row * 512 + c16 * 16) ^ ((row & 7) << 4);
      *(int32x4*)(lds + 16384 + byte) = pv[q];
    }
#pragma unroll
    for (int r = 0; r < 8; ++r) {
      floatx4 xs;
      xs[0] = xv[r][0] * rsm[0]; xs[1] = xv[r][1] * rsm[1];
      xs[2] = xv[r][2] * rsm[2]; xs[3] = xv[r][3] * rsm[3];
      float m4 = fmaxf(fmaxf(fabsf(xs[0]), fabsf(xs[1])),
                       fmaxf(fabsf(xs[2]), fabsf(xs[3])));
      m4 = fmaxf(m4, __shfl_xor(m4, 1, 64));
      m4 = fmaxf(m4, __shfl_xor(m4, 2, 64));
      m4 = fmaxf(m4, __shfl_xor(m4, 4, 64));
      m4 = fmaxf(m4, __shfl_xor(m4, 8, 64));   // 16-lane span = group of 64 channels
      float ascale = m4 > 0.f ? m4 / 7.0f : 1.0f;
      float rq = 1.0f / ascale;
      int tokrel = t0rel + wid * 8 + r;
      alignas(8) _Float16 hq[4];
#pragma unroll
      for (int b = 0; b < 4; ++b) {
        float qf = fminf(7.f, fmaxf(-8.f, rintf(xs[b] * rq)));
        hq[b] = (_Float16)(qf * ascale);       // dequantized activation, RN f16
      }
      *(int32x2*)((char*)xdq + ((size_t)tokrel * INF + kc * 256 + lane * 4) * 2) =
          *(const int32x2*)hq;
      unsigned lo = (unsigned)f2bf(xs[0]) | ((unsigned)f2bf(xs[1]) << 16);
      unsigned hi = (unsigned)f2bf(xs[2]) | ((unsigned)f2bf(xs[3]) << 16);
      int lrow = wid * 8 + r;
      int xbyte = (lrow * 512 + lane * 8) ^ ((lrow & 7) << 4);
      int32x2 wv; wv[0] = (int)lo; wv[1] = (int)hi;
      *(int32x2*)(lds + xbyte) = wv;
    }
    __syncthreads();
    if (kc + 1 < 8) issue_loads(kc + 1);
#pragma unroll
    for (int ks = 0; ks < 8; ++ks) {
      int arow = mi * 16 + (lane & 15);
      int ab = (arow * 512 + ks * 64 + ((lane >> 4) << 4)) ^ ((arow & 7) << 4);
      bf16x8 av = *(const bf16x8*)(lds + ab);
      int brow = ni * 16 + (lane & 15);
      int bb = (brow * 512 + ks * 64 + ((lane >> 4) << 4)) ^ ((brow & 7) << 4);
      bf16x8 bv = *(const bf16x8*)(lds + 16384 + bb);
      acc = __builtin_amdgcn_mfma_f32_16x16x32_bf16(av, bv, acc, 0, 0, 0);
    }
    __syncthreads();
  }

  int trow = tbase + t0rel + mi * 16 + ((lane >> 4) << 2);
  int col = ni * 16 + (lane & 15);
#pragma unroll
  for (int r = 0; r < 4; ++r)
    tdown[(size_t)(trow + r) * RANK + col] = acc[r];
}

// ---------------- kernel 3: f16 MFMA GEMM, 256x256, B-in-registers, A-only LDS ----
// 512 thr / 8 waves (2M x 4N), per-wave 128x64, 64 MFMA/K-tile/wave.
// LDS 96KB: A only, 3 bufs x [256 rows][128B swz].  B frags load GLOBAL->REG
// (B panel 2MB/XCD = L2-resident), double-buffered one K-tile ahead.
// LDS traffic/tile: 128KB A-reads + 32KB A-writes = 160KB (was 262KB).
// Per tile t: vmcnt(4) [drains B(t), leaves stageA(t+1..2) in flight]; barrier;
//   {read A sub-chunk p+1  ||  MFMA sub-chunk p} x4 with lgkmcnt(4) counted waits;
//   B(t+1)->bnext + stageA(t+2) issued after first A chunk (order pinned: B first).
// FIFO at top of t = [B(t):8, stageA(t+1):4] -> vmcnt(4). vmcnt(0) only at t=31.
__global__ __launch_bounds__(512, 2) void gemm_kernel(
    const _Float16* __restrict__ xdq, const _Float16* __restrict__ wdq,
    const float* __restrict__ tdown, const float* __restrict__ pu,
    const float* __restrict__ bias, float* __restrict__ y,
    int tbase, int mPanels) {
  __shared__ char smem[98304];

  int tid = threadIdx.x;
  int lane = tid & 63;
  int wid = tid >> 6;
  int wm = wid >> 2, wn = wid & 3;             // 2M x 4N; wave out 128x64

  // grid: 8 XCDs x (2 npan x mPanels/2). Per-XCD B set = 2x256 rows = 2 MB (L2-fit).
  int s = blockIdx.x;
  int xcd = s & 7, idx = s >> 3;
  int npan = ((xcd & 3) << 1) + (idx & 1);
  int mpan = (xcd >> 2) * (mPanels >> 1) + (idx >> 1);
  int o0 = npan * BN;
  int t0rel = mpan * BM;
  int t0abs = tbase + t0rel;

  floatx4 acc[8][4];
#pragma unroll
  for (int m = 0; m < 8; ++m)
#pragma unroll
    for (int n = 0; n < 4; ++n) acc[m][n] = (floatx4){0.f, 0.f, 0.f, 0.f};

  // stage full A K-tile (32 KB = 2048 granules, 4 per thread), linear dest,
  // pre-swizzled source slot ^= row&7 (both-sides rule).
  auto stageA = [&](int g) {
    int bufb = (g % 3) * 32768;
#pragma unroll
    for (int i = 0; i < 4; ++i) {
      int f = i * 512 + tid;
      int row = f >> 3, sl = (f & 7) ^ (row & 7);
      gload_lds16((const char*)xdq + (size_t)(t0rel + row) * (INF * 2) + g * 128 + sl * 16,
                  smem + bufb + i * 8192 + wid * 1024);
    }
  };

  // B fragment global base: col = o0 + wn*64 + nf*16 + (lane&15); k-chunk (lane>>4)*8
  const char* bbase_g = (const char*)wdq +
      (size_t)(o0 + (wn << 6) + (lane & 15)) * (INF * 2) + ((lane >> 4) << 4);

  f16x8 b0[4][2], b1[4][2];
  auto loadB = [&](int g, f16x8 (&b)[4][2]) {
#pragma unroll
    for (int nf = 0; nf < 4; ++nf)
#pragma unroll
      for (int ks = 0; ks < 2; ++ks)
        b[nf][ks] = *(const f16x8*)(bbase_g + (size_t)nf * 65536 + g * 128 + ks * 64);
  };

  // A fragment read bases (swizzled): row = wm*128 + j*16 + (lane&15); row&7 = l&7
  int l = lane & 15;
  int abase[2];
#pragma unroll
  for (int ks = 0; ks < 2; ++ks)
    abase[ks] = (wm * 128 + l) * 128 + ((((ks << 2) + (lane >> 4)) ^ (l & 7)) << 4);

  // prologue: B(0) FIRST, then A(0), A(1)  -> FIFO [B0:8, A0:4, A1:4]
  loadB(0, b0);
  __builtin_amdgcn_sched_barrier(0);
  stageA(0);
  stageA(1);

  f16x8 ar[4][2];   // two j-pair chunks live at a time

  auto body = [&](int t, f16x8 (&bcur)[4][2], f16x8 (&bnext)[4][2]) {
    if (t == NPER - 1) asm volatile("s_waitcnt vmcnt(0)" ::: "memory");
    else               asm volatile("s_waitcnt vmcnt(4)" ::: "memory");
    __builtin_amdgcn_s_barrier();
    __builtin_amdgcn_sched_barrier(0);

    const char* sb = smem + (t % 3) * 32768;

    // chunk 0 reads (j=0,1)
#pragma unroll
    for (int jj = 0; jj < 2; ++jj) {
      ar[jj][0] = *(const f16x8*)(sb + abase[0] + jj * 2048);
      ar[jj][1] = *(const f16x8*)(sb + abase[1] + jj * 2048);
    }
    // issue next-tile B (first!) then A stage (order pinned for vmcnt math)
    if (t + 1 < NPER) loadB(t + 1, bnext);
    __builtin_amdgcn_sched_barrier(0);
    if (t + 2 < NPER) stageA(t + 2);
    __builtin_amdgcn_sched_barrier(0);
    // chunk 1 reads (j=2,3)
#pragma unroll
    for (int jj = 0; jj < 2; ++jj) {
      ar[2 + jj][0] = *(const f16x8*)(sb + abase[0] + (2 + jj) * 2048);
      ar[2 + jj][1] = *(const f16x8*)(sb + abase[1] + (2 + jj) * 2048);
    }

#pragma unroll
    for (int p = 0; p < 4; ++p) {
      // wait for chunk p (4 reads), leave chunk p+1 (4) in flight
      if (p < 3) asm volatile("s_waitcnt lgkmcnt(4)" ::: "memory");
      else       asm volatile("s_waitcnt lgkmcnt(0)" ::: "memory");
      __builtin_amdgcn_sched_barrier(0);
      int sel = p & 1;               // chunk p lives in ar[sel*2 .. sel*2+1]
      __builtin_amdgcn_s_setprio(1);
#pragma unroll
      for (int jj = 0; jj < 2; ++jj)
#pragma unroll
        for (int nf = 0; nf < 4; ++nf) {
          acc[p * 2 + jj][nf] = __builtin_amdgcn_mfma_f32_16x16x32_f16(
              ar[sel * 2 + jj][0], bcur[nf][0], acc[p * 2 + jj][nf], 0, 0, 0);
          acc[p * 2 + jj][nf] = __builtin_amdgcn_mfma_f32_16x16x32_f16(
              ar[sel * 2 + jj][1], bcur[nf][1], acc[p * 2 + jj][nf], 0, 0, 0);
        }
      __builtin_amdgcn_s_setprio(0);
      // issue chunk p+2 reads into the slots just freed (chunk p's)
      if (p < 2) {
#pragma unroll
        for (int jj = 0; jj < 2; ++jj) {
          ar[sel * 2 + jj][0] = *(const f16x8*)(sb + abase[0] + ((p + 2) * 2 + jj) * 2048);
          ar[sel * 2 + jj][1] = *(const f16x8*)(sb + abase[1] + ((p + 2) * 2 + jj) * 2048);
        }
      }
    }
  };

  for (int i = 0; i < NPER / 2; ++i) {
    body(2 * i, b0, b1);
    body(2 * i + 1, b1, b0);
  }

  __syncthreads();   // full sync before reusing smem for epilogue

  // epilogue: low-rank via one bf16 MFMA pass (K = RANK = 32) + bias
  unsigned short* td_lds = (unsigned short*)smem;           // [256][32] bf16
  unsigned short* pu_lds = (unsigned short*)(smem + 16384); // [256][32] bf16
  {
    int row = tid >> 1, h = (tid & 1) * 16;
    const float* ts = tdown + (size_t)(t0abs + row) * RANK + h;
    const float* ps = pu + (size_t)(o0 + row) * RANK + h;
    unsigned tw[8], pw[8];
#pragma unroll
    for (int q = 0; q < 4; ++q) {
      float4 v = *(const float4*)(ts + q * 4);
      tw[q * 2 + 0] = (unsigned)f2bf(v.x) | ((unsigned)f2bf(v.y) << 16);
      tw[q * 2 + 1] = (unsigned)f2bf(v.z) | ((unsigned)f2bf(v.w) << 16);
      float4 p = *(const float4*)(ps + q * 4);
      pw[q * 2 + 0] = (unsigned)f2bf(p.x) | ((unsigned)f2bf(p.y) << 16);
      pw[q * 2 + 1] = (unsigned)f2bf(p.z) | ((unsigned)f2bf(p.w) << 16);
    }
    int4 s0, s1;
    s0.x = (int)tw[0]; s0.y = (int)tw[1]; s0.z = (int)tw[2]; s0.w = (int)tw[3];
    s1.x = (int)tw[4]; s1.y = (int)tw[5]; s1.z = (int)tw[6]; s1.w = (int)tw[7];
    *(int4*)(td_lds + row * 32 + h) = s0;
    *(int4*)(td_lds + row * 32 + h + 8) = s1;
    s0.x = (int)pw[0]; s0.y = (int)pw[1]; s0.z = (int)pw[2]; s0.w = (int)pw[3];
    s1.x = (int)pw[4]; s1.y = (int)pw[5]; s1.z = (int)pw[6]; s1.w = (int)pw[7];
    *(int4*)(pu_lds + row * 32 + h) = s0;
    *(int4*)(pu_lds + row * 32 + h + 8) = s1;
  }
  __syncthreads();

  bf16x8 ta[8], pb4[4];
  int koff8 = (lane >> 4) << 3;
#pragma unroll
  for (int m = 0; m < 8; ++m)
    ta[m] = *(const bf16x8*)&td_lds[((wm << 7) + (m << 4) + (lane & 15)) * 32 + koff8];
#pragma unroll
  for (int n = 0; n < 4; ++n)
    pb4[n] = *(const bf16x8*)&pu_lds[((wn << 6) + (n << 4) + (lane & 15)) * 32 + koff8];

#pragma unroll
  for (int n = 0; n < 4; ++n) {
    int oc = o0 + (wn << 6) + (n << 4) + (lane & 15);
    float bv = bias[oc];
#pragma unroll
    for (int m = 0; m < 8; ++m) {
      floatx4 c = acc[m][n];
      c = __builtin_amdgcn_mfma_f32_16x16x32_bf16(ta[m], pb4[n], c, 0, 0, 0);
#pragma unroll
      for (int r = 0; r < 4; ++r) {
        int tr = t0abs + (wm << 7) + (m << 4) + ((lane >> 4) << 2) + r;
        y[(size_t)tr * OUTF + oc] = c[r] + bv;
      }
    }
  }
}

extern "C" void kernel_launch(void* const* d_in, const int* in_sizes, int n_in,
                              void* d_out, int out_size, void* d_ws, size_t ws_size,
                              hipStream_t stream) {
  const float* x      = (const float*)d_in[0];
  const int*   qw     = (const int*)d_in[1];
  const float* wsc    = (const float*)d_in[2];
  const float* smooth = (const float*)d_in[3];
  const float* bias   = (const float*)d_in[4];
  const float* pd     = (const float*)d_in[5];
  const float* pu     = (const float*)d_in[6];
  float* y = (float*)d_out;

  char* ws = (char*)d_ws;
  unsigned short* pdT = (unsigned short*)((char*)d_out + (64u << 20));

  if (ws_size >= 77594624ULL) {
    // full path: xdq f16 [16384][2048] = 67.1 MB | wdq 8.39 MB | tdown 2.1 MB
    _Float16* xdq = (_Float16*)ws;
    _Float16* wdq = (_Float16*)(ws + 67108864);
    float* tdown  = (float*)(ws + 67108864 + 8388608);
    unpack_kernel<<<512, 256, 0, stream>>>(qw, wsc, wdq);
    prep_pdT<<<256, 256, 0, stream>>>(pd, pdT);
    quant_kernel<<<TOKENS / 32, 256, 0, stream>>>(x, smooth, pdT, xdq, tdown, 0);
    gemm_kernel<<<8 * (TOKENS / BM), 512, 0, stream>>>(
        xdq, wdq, tdown, pu, bias, y, 0, TOKENS / BM);
  } else {
    // chunked fallback: xdq_half 33.55 MB | wdq 8.39 MB | tdown 2.1 MB = 44.04 MB
    _Float16* xdq = (_Float16*)ws;
    _Float16* wdq = (_Float16*)(ws + 33554432);
    float* tdown  = (float*)(ws + 33554432 + 8388608);
    unpack_kernel<<<512, 256, 0, stream>>>(qw, wsc, wdq);
    prep_pdT<<<256, 256, 0, stream>>>(pd, pdT);
    for (int c = 0; c < 2; ++c) {
      int tbase = c * THALF;
      quant_kernel<<<THALF / 32, 256, 0, stream>>>(x, smooth, pdT, xdq, tdown, tbase);
      gemm_kernel<<<8 * (THALF / BM), 512, 0, stream>>>(
          xdq, wdq, tdown, pu, bias, y, tbase, THALF / BM);
    }
  }
}

// Round 13
// 193.985 us; speedup vs baseline: 1.2962x; 1.2962x over previous
//
#include <hip/hip_runtime.h>

#define TOKENS 16384
#define THALF 8192
#define INF 2048
#define OUTF 2048
#define RANK 32
#define BM 256
#define BN 256
#define NPER 32     // 2048 / 64 f16 per K-tile

typedef int   int32x4  __attribute__((ext_vector_type(4)));
typedef int   int32x2  __attribute__((ext_vector_type(2)));
typedef float floatx4  __attribute__((ext_vector_type(4)));
typedef short bf16x8   __attribute__((ext_vector_type(8)));
typedef _Float16 f16x8 __attribute__((ext_vector_type(8)));

typedef __attribute__((address_space(1))) const void gconst_t;
typedef __attribute__((address_space(3))) void ldsv_t;

__device__ __forceinline__ void gload_lds16(const void* g, void* l) {
  __builtin_amdgcn_global_load_lds((gconst_t*)g, (ldsv_t*)l, 16, 0, 0);
}

__device__ __forceinline__ unsigned short f2bf(float f) {
  unsigned u = __float_as_uint(f);
  unsigned r = (u + 0x7FFFu + ((u >> 16) & 1u)) >> 16;
  return (unsigned short)r;
}

// ---------------- kernel 1: (merged) unpack int4->wdq f16  +  pd->pdT bf16 ----------------
// blocks 0..511: unpack+fold wscales; blocks 512..767: pdT transpose.
__global__ __launch_bounds__(256) void prep_kernel(const int* __restrict__ qw,
                                                   const float* __restrict__ wsc,
                                                   _Float16* __restrict__ wdq,
                                                   const float* __restrict__ pd,
                                                   unsigned short* __restrict__ pdT) {
  int b = blockIdx.x;
  if (b < 512) {
    int idx = b * 256 + threadIdx.x;            // 131072 threads, 32 channels each
    int o = idx >> 6;
    int ch = idx & 63;                          // 32-channel chunk -> group = ch>>1
    float ws = wsc[(size_t)(ch >> 1) * OUTF + o];
    const int4* src = (const int4*)qw + (size_t)idx * 4;
    _Float16* dst = wdq + (size_t)o * INF + ch * 32;
#pragma unroll
    for (int q = 0; q < 4; ++q) {
      int4 v = src[q];
      int e[4] = {v.x, v.y, v.z, v.w};
      alignas(16) _Float16 h[8];
#pragma unroll
      for (int j = 0; j < 4; ++j) {
        int lo = ((int)((unsigned)e[j] << 28)) >> 28;
        int hi = ((int)((unsigned)e[j] << 24)) >> 28;
        h[2 * j]     = (_Float16)((float)lo * ws);
        h[2 * j + 1] = (_Float16)((float)hi * ws);
      }
      *(int4*)(dst + q * 8) = *(const int4*)h;
    }
  } else {
    int idx = (b - 512) * 256 + threadIdx.x;    // 65536 elements
    int r = idx >> 11, c = idx & 2047;
    pdT[idx] = f2bf(pd[(size_t)c * RANK + r]);
  }
}

// ---------------- kernel 2: coalesced quant -> xdq f16 + MFMA down-projection ----------------
__global__ __launch_bounds__(256) void quant_kernel(
    const float* __restrict__ x, const float* __restrict__ smooth,
    const unsigned short* __restrict__ pdT,
    _Float16* __restrict__ xdq, float* __restrict__ tdown, int tbase) {
  __shared__ char lds[32768];   // xs [32][256] bf16 swz @0, pdT chunk [32][256] bf16 swz @16384
  int tid = threadIdx.x, lane = tid & 63, wid = tid >> 6;
  int t0rel = blockIdx.x * 32;
  int mi = wid >> 1, ni = wid & 1;
  floatx4 acc = {0.f, 0.f, 0.f, 0.f};

  floatx4 xv[8];
  floatx4 sm;
  int32x4 pv[4];

  auto issue_loads = [&](int kc) {
    const float* xb = x + (size_t)(tbase + t0rel + wid * 8) * INF + kc * 256 + lane * 4;
#pragma unroll
    for (int r = 0; r < 8; ++r) xv[r] = *(const floatx4*)(xb + r * INF);
    sm = *(const floatx4*)(smooth + kc * 256 + lane * 4);
#pragma unroll
    for (int q = 0; q < 4; ++q) {
      int flat = tid + q * 256;
      int row = flat >> 5, c16 = flat & 31;
      pv[q] = *(const int32x4*)((const char*)pdT + (size_t)row * 4096 + kc * 512 + c16 * 16);
    }
  };

  issue_loads(0);

  for (int kc = 0; kc < 8; ++kc) {
    floatx4 rsm;
    rsm[0] = 1.0f / sm[0]; rsm[1] = 1.0f / sm[1];
    rsm[2] = 1.0f / sm[2]; rsm[3] = 1.0f / sm[3];
#pragma unroll
    for (int q = 0; q < 4; ++q) {
      int flat = tid + q * 256;
      int row = flat >> 5, c16 = flat & 31;
      int byte = (row * 512 + c16 * 16) ^ ((row & 7) << 4);
      *(int32x4*)(lds + 16384 + byte) = pv[q];
    }
#pragma unroll
    for (int r = 0; r < 8; ++r) {
      floatx4 xs;
      xs[0] = xv[r][0] * rsm[0]; xs[1] = xv[r][1] * rsm[1];
      xs[2] = xv[r][2] * rsm[2]; xs[3] = xv[r][3] * rsm[3];
      float m4 = fmaxf(fmaxf(fabsf(xs[0]), fabsf(xs[1])),
                       fmaxf(fabsf(xs[2]), fabsf(xs[3])));
      m4 = fmaxf(m4, __shfl_xor(m4, 1, 64));
      m4 = fmaxf(m4, __shfl_xor(m4, 2, 64));
      m4 = fmaxf(m4, __shfl_xor(m4, 4, 64));
      m4 = fmaxf(m4, __shfl_xor(m4, 8, 64));   // 16-lane span = group of 64 channels
      float ascale = m4 > 0.f ? m4 / 7.0f : 1.0f;
      float rq = 1.0f / ascale;
      int tokrel = t0rel + wid * 8 + r;
      alignas(8) _Float16 hq[4];
#pragma unroll
      for (int b = 0; b < 4; ++b) {
        float qf = fminf(7.f, fmaxf(-8.f, rintf(xs[b] * rq)));
        hq[b] = (_Float16)(qf * ascale);       // dequantized activation, RN f16
      }
      *(int32x2*)((char*)xdq + ((size_t)tokrel * INF + kc * 256 + lane * 4) * 2) =
          *(const int32x2*)hq;
      unsigned lo = (unsigned)f2bf(xs[0]) | ((unsigned)f2bf(xs[1]) << 16);
      unsigned hi = (unsigned)f2bf(xs[2]) | ((unsigned)f2bf(xs[3]) << 16);
      int lrow = wid * 8 + r;
      int xbyte = (lrow * 512 + lane * 8) ^ ((lrow & 7) << 4);
      int32x2 wv; wv[0] = (int)lo; wv[1] = (int)hi;
      *(int32x2*)(lds + xbyte) = wv;
    }
    __syncthreads();
    if (kc + 1 < 8) issue_loads(kc + 1);
#pragma unroll
    for (int ks = 0; ks < 8; ++ks) {
      int arow = mi * 16 + (lane & 15);
      int ab = (arow * 512 + ks * 64 + ((lane >> 4) << 4)) ^ ((arow & 7) << 4);
      bf16x8 av = *(const bf16x8*)(lds + ab);
      int brow = ni * 16 + (lane & 15);
      int bb = (brow * 512 + ks * 64 + ((lane >> 4) << 4)) ^ ((brow & 7) << 4);
      bf16x8 bv = *(const bf16x8*)(lds + 16384 + bb);
      acc = __builtin_amdgcn_mfma_f32_16x16x32_bf16(av, bv, acc, 0, 0, 0);
    }
    __syncthreads();
  }

  int trow = tbase + t0rel + mi * 16 + ((lane >> 4) << 2);
  int col = ni * 16 + (lane & 15);
#pragma unroll
  for (int r = 0; r < 4; ++r)
    tdown[(size_t)(trow + r) * RANK + col] = acc[r];
}

// ---------------- kernel 3: f16 MFMA GEMM, 256x256 tile, BK=64, 4-phase K-tile ----
// (reverted verbatim to the best-measured round-9 configuration: 148.9 us)
// 512 thr / 8 waves (2M x 4N), per-wave 128x64 out, 64 MFMA/K-tile/wave.
// LDS 128KB: slot s in {0,1}: A-half h [128 rows][128B] @ s*64K + h*16K,
//                              B-half h @ s*64K + 32K + h*16K.
// Swizzle: 16B-granule slot ^= (row&7), pre-swizzled global source + swizzled read.
// Stage: 1 half-tile (2 gload_lds16/thread) per phase. Steady stage order within
// tile t: p0 Bh1(t+1), p1 Ah1(t+1), p2 Bh0(t+2), p3 Ah0(t+2). Boundary wait
// vmcnt(4) (leaves newest 2 half-tiles in flight); vmcnt(0) only at last tile.
__global__ __launch_bounds__(512, 2) void gemm_kernel(
    const _Float16* __restrict__ xdq, const _Float16* __restrict__ wdq,
    const float* __restrict__ tdown, const float* __restrict__ pu,
    const float* __restrict__ bias, float* __restrict__ y,
    int tbase, int mPanels) {
  __shared__ char smem[131072];

  int tid = threadIdx.x;
  int lane = tid & 63;
  int wid = tid >> 6;
  int wm = wid >> 2, wn = wid & 3;             // 2M x 4N; wave out 128x64

  // grid: 8 XCDs x (2 npan x mPanels/2). Per-XCD B set = 2x256 rows = 2 MB (L2-fit).
  int s = blockIdx.x;
  int xcd = s & 7, idx = s >> 3;
  int npan = ((xcd & 3) << 1) + (idx & 1);
  int mpan = (xcd >> 2) * (mPanels >> 1) + (idx >> 1);
  int o0 = npan * BN;
  int t0rel = mpan * BM;
  int t0abs = tbase + t0rel;

  floatx4 acc[8][4];
#pragma unroll
  for (int m = 0; m < 8; ++m)
#pragma unroll
    for (int n = 0; n < 4; ++n) acc[m][n] = (floatx4){0.f, 0.f, 0.f, 0.f};

  // stage one half-tile (16 KB = 1024 granules, 2 per thread)
  auto stageA = [&](int g, int h) {
    int dst = (g & 1) * 65536 + h * 16384;
#pragma unroll
    for (int i = 0; i < 2; ++i) {
      int f = i * 512 + tid;
      int row = f >> 3, sl = (f & 7) ^ (row & 7);
      gload_lds16((const char*)xdq + (size_t)(t0rel + h * 128 + row) * (INF * 2) + g * 128 + sl * 16,
                  smem + dst + i * 8192 + wid * 1024);
    }
  };
  auto stageB = [&](int g, int h) {
    int dst = (g & 1) * 65536 + 32768 + h * 16384;
#pragma unroll
    for (int i = 0; i < 2; ++i) {
      int f = i * 512 + tid;
      int row = f >> 3, sl = (f & 7) ^ (row & 7);
      gload_lds16((const char*)wdq + (size_t)(o0 + h * 128 + row) * (INF * 2) + g * 128 + sl * 16,
                  smem + dst + i * 8192 + wid * 1024);
    }
  };

  // fragment read bases: (row&7) == (lane&15)&7 independent of frag index ->
  // 2 base offsets per operand, frag index folds into the ds_read immediate.
  int l = lane & 15;
  int abase[2], bbase[2];
#pragma unroll
  for (int ks = 0; ks < 2; ++ks) {
    abase[ks] = wm * 16384 + l * 128 + ((((ks << 2) + (lane >> 4)) ^ (l & 7)) << 4);
    bbase[ks] = 32768 + (wn >> 1) * 16384 + ((wn & 1) * 64 + l) * 128 +
                ((((ks << 2) + (lane >> 4)) ^ (l & 7)) << 4);
  }

  // prologue: 6 half-tiles = 12 loads (tile0 complete + Bh0/Ah0 of tile1)
  stageB(0, 0); stageA(0, 0); stageB(0, 1); stageA(0, 1);
  stageB(1, 0); stageA(1, 0);

  f16x8 areg[4][2], breg0[2][2], breg1[2][2];

  for (int t = 0; t < NPER; ++t) {
    if (t == NPER - 1) asm volatile("s_waitcnt vmcnt(0)" ::: "memory");
    else               asm volatile("s_waitcnt vmcnt(4)" ::: "memory");
    __builtin_amdgcn_s_barrier();
    __builtin_amdgcn_sched_barrier(0);

    const char* sb = smem + (t & 1) * 65536;
    const char* pa0 = sb + abase[0];
    const char* pa1 = sb + abase[1];
    const char* pb0 = sb + bbase[0];
    const char* pb1 = sb + bbase[1];

    // ---- phase 0: read A frags 0-3 + B frags 0-1; stage Bh1(t+1); MFMA A03xB01 ----
#pragma unroll
    for (int j = 0; j < 4; ++j) {
      areg[j][0] = *(const f16x8*)(pa0 + j * 2048);
      areg[j][1] = *(const f16x8*)(pa1 + j * 2048);
    }
#pragma unroll
    for (int nf = 0; nf < 2; ++nf) {
      breg0[nf][0] = *(const f16x8*)(pb0 + nf * 2048);
      breg0[nf][1] = *(const f16x8*)(pb1 + nf * 2048);
    }
    if (t + 1 < NPER) stageB(t + 1, 1);
    asm volatile("s_waitcnt lgkmcnt(0)" ::: "memory");
    __builtin_amdgcn_sched_barrier(0);
    __builtin_amdgcn_s_setprio(1);
#pragma unroll
    for (int j = 0; j < 4; ++j)
#pragma unroll
      for (int nf = 0; nf < 2; ++nf) {
        acc[j][nf] = __builtin_amdgcn_mfma_f32_16x16x32_f16(areg[j][0], breg0[nf][0], acc[j][nf], 0, 0, 0);
        acc[j][nf] = __builtin_amdgcn_mfma_f32_16x16x32_f16(areg[j][1], breg0[nf][1], acc[j][nf], 0, 0, 0);
      }
    __builtin_amdgcn_s_setprio(0);
    __builtin_amdgcn_s_barrier();

    // ---- phase 1: read B frags 2-3; stage Ah1(t+1); MFMA A03xB23 ----
#pragma unroll
    for (int nf = 0; nf < 2; ++nf) {
      breg1[nf][0] = *(const f16x8*)(pb0 + (2 + nf) * 2048);
      breg1[nf][1] = *(const f16x8*)(pb1 + (2 + nf) * 2048);
    }
    if (t + 1 < NPER) stageA(t + 1, 1);
    asm volatile("s_waitcnt lgkmcnt(0)" ::: "memory");
    __builtin_amdgcn_sched_barrier(0);
    __builtin_amdgcn_s_setprio(1);
#pragma unroll
    for (int j = 0; j < 4; ++j)
#pragma unroll
      for (int nf = 0; nf < 2; ++nf) {
        acc[j][2 + nf] = __builtin_amdgcn_mfma_f32_16x16x32_f16(areg[j][0], breg1[nf][0], acc[j][2 + nf], 0, 0, 0);
        acc[j][2 + nf] = __builtin_amdgcn_mfma_f32_16x16x32_f16(areg[j][1], breg1[nf][1], acc[j][2 + nf], 0, 0, 0);
      }
    __builtin_amdgcn_s_setprio(0);
    __builtin_amdgcn_s_barrier();

    // ---- phase 2: read A frags 4-7; stage Bh0(t+2); MFMA A47xB23 ----
#pragma unroll
    for (int j = 0; j < 4; ++j) {
      areg[j][0] = *(const f16x8*)(pa0 + (4 + j) * 2048);
      areg[j][1] = *(const f16x8*)(pa1 + (4 + j) * 2048);
    }
    if (t + 2 < NPER) stageB(t + 2, 0);
    asm volatile("s_waitcnt lgkmcnt(0)" ::: "memory");
    __builtin_amdgcn_sched_barrier(0);
    __builtin_amdgcn_s_setprio(1);
#pragma unroll
    for (int j = 0; j < 4; ++j)
#pragma unroll
      for (int nf = 0; nf < 2; ++nf) {
        acc[4 + j][2 + nf] = __builtin_amdgcn_mfma_f32_16x16x32_f16(areg[j][0], breg1[nf][0], acc[4 + j][2 + nf], 0, 0, 0);
        acc[4 + j][2 + nf] = __builtin_amdgcn_mfma_f32_16x16x32_f16(areg[j][1], breg1[nf][1], acc[4 + j][2 + nf], 0, 0, 0);
      }
    __builtin_amdgcn_s_setprio(0);
    __builtin_amdgcn_s_barrier();

    // ---- phase 3: stage Ah0(t+2); MFMA A47xB01 ----
    if (t + 2 < NPER) stageA(t + 2, 0);
    __builtin_amdgcn_s_setprio(1);
#pragma unroll
    for (int j = 0; j < 4; ++j)
#pragma unroll
      for (int nf = 0; nf < 2; ++nf) {
        acc[4 + j][nf] = __builtin_amdgcn_mfma_f32_16x16x32_f16(areg[j][0], breg0[nf][0], acc[4 + j][nf], 0, 0, 0);
        acc[4 + j][nf] = __builtin_amdgcn_mfma_f32_16x16x32_f16(areg[j][1], breg0[nf][1], acc[4 + j][nf], 0, 0, 0);
      }
    __builtin_amdgcn_s_setprio(0);
    __builtin_amdgcn_s_barrier();
  }

  __syncthreads();   // full sync before reusing smem for epilogue

  // epilogue: low-rank via one bf16 MFMA pass (K = RANK = 32) + bias
  unsigned short* td_lds = (unsigned short*)smem;           // [256][32] bf16
  unsigned short* pu_lds = (unsigned short*)(smem + 16384); // [256][32] bf16
  {
    int row = tid >> 1, h = (tid & 1) * 16;
    const float* ts = tdown + (size_t)(t0abs + row) * RANK + h;
    const float* ps = pu + (size_t)(o0 + row) * RANK + h;
    unsigned tw[8], pw[8];
#pragma unroll
    for (int q = 0; q < 4; ++q) {
      float4 v = *(const float4*)(ts + q * 4);
      tw[q * 2 + 0] = (unsigned)f2bf(v.x) | ((unsigned)f2bf(v.y) << 16);
      tw[q * 2 + 1] = (unsigned)f2bf(v.z) | ((unsigned)f2bf(v.w) << 16);
      float4 p = *(const float4*)(ps + q * 4);
      pw[q * 2 + 0] = (unsigned)f2bf(p.x) | ((unsigned)f2bf(p.y) << 16);
      pw[q * 2 + 1] = (unsigned)f2bf(p.z) | ((unsigned)f2bf(p.w) << 16);
    }
    int4 s0, s1;
    s0.x = (int)tw[0]; s0.y = (int)tw[1]; s0.z = (int)tw[2]; s0.w = (int)tw[3];
    s1.x = (int)tw[4]; s1.y = (int)tw[5]; s1.z = (int)tw[6]; s1.w = (int)tw[7];
    *(int4*)(td_lds + row * 32 + h) = s0;
    *(int4*)(td_lds + row * 32 + h + 8) = s1;
    s0.x = (int)pw[0]; s0.y = (int)pw[1]; s0.z = (int)pw[2]; s0.w = (int)pw[3];
    s1.x = (int)pw[4]; s1.y = (int)pw[5]; s1.z = (int)pw[6]; s1.w = (int)pw[7];
    *(int4*)(pu_lds + row * 32 + h) = s0;
    *(int4*)(pu_lds + row * 32 + h + 8) = s1;
  }
  __syncthreads();

  bf16x8 ta[8], pb4[4];
  int koff8 = (lane >> 4) << 3;
#pragma unroll
  for (int m = 0; m < 8; ++m)
    ta[m] = *(const bf16x8*)&td_lds[((wm << 7) + (m << 4) + (lane & 15)) * 32 + koff8];
#pragma unroll
  for (int n = 0; n < 4; ++n)
    pb4[n] = *(const bf16x8*)&pu_lds[((wn << 6) + (n << 4) + (lane & 15)) * 32 + koff8];

#pragma unroll
  for (int n = 0; n < 4; ++n) {
    int oc = o0 + (wn << 6) + (n << 4) + (lane & 15);
    float bv = bias[oc];
#pragma unroll
    for (int m = 0; m < 8; ++m) {
      floatx4 c = acc[m][n];
      c = __builtin_amdgcn_mfma_f32_16x16x32_bf16(ta[m], pb4[n], c, 0, 0, 0);
#pragma unroll
      for (int r = 0; r < 4; ++r) {
        int tr = t0abs + (wm << 7) + (m << 4) + ((lane >> 4) << 2) + r;
        y[(size_t)tr * OUTF + oc] = c[r] + bv;
      }
    }
  }
}

extern "C" void kernel_launch(void* const* d_in, const int* in_sizes, int n_in,
                              void* d_out, int out_size, void* d_ws, size_t ws_size,
                              hipStream_t stream) {
  const float* x      = (const float*)d_in[0];
  const int*   qw     = (const int*)d_in[1];
  const float* wsc    = (const float*)d_in[2];
  const float* smooth = (const float*)d_in[3];
  const float* bias   = (const float*)d_in[4];
  const float* pd     = (const float*)d_in[5];
  const float* pu     = (const float*)d_in[6];
  float* y = (float*)d_out;

  char* ws = (char*)d_ws;
  unsigned short* pdT = (unsigned short*)((char*)d_out + (64u << 20));

  if (ws_size >= 77594624ULL) {
    // full path: xdq f16 [16384][2048] = 67.1 MB | wdq 8.39 MB | tdown 2.1 MB
    _Float16* xdq = (_Float16*)ws;
    _Float16* wdq = (_Float16*)(ws + 67108864);
    float* tdown  = (float*)(ws + 67108864 + 8388608);
    prep_kernel<<<768, 256, 0, stream>>>(qw, wsc, wdq, pd, pdT);
    quant_kernel<<<TOKENS / 32, 256, 0, stream>>>(x, smooth, pdT, xdq, tdown, 0);
    gemm_kernel<<<8 * (TOKENS / BM), 512, 0, stream>>>(
        xdq, wdq, tdown, pu, bias, y, 0, TOKENS / BM);
  } else {
    // chunked fallback: xdq_half 33.55 MB | wdq 8.39 MB | tdown 2.1 MB = 44.04 MB
    _Float16* xdq = (_Float16*)ws;
    _Float16* wdq = (_Float16*)(ws + 33554432);
    float* tdown  = (float*)(ws + 33554432 + 8388608);
    prep_kernel<<<768, 256, 0, stream>>>(qw, wsc, wdq, pd, pdT);
    for (int c = 0; c < 2; ++c) {
      int tbase = c * THALF;
      quant_kernel<<<THALF / 32, 256, 0, stream>>>(x, smooth, pdT, xdq, tdown, tbase);
      gemm_kernel<<<8 * (THALF / BM), 512, 0, stream>>>(
          xdq, wdq, tdown, pu, bias, y, tbase, THALF / BM);
    }
  }
}